// Round 2
// baseline (747.480 us; speedup 1.0000x reference)
//
#include <hip/hip_runtime.h>
#include <cstdint>

#define DEV __device__ __forceinline__

constexpr int Bz = 8, Tz = 4096, Cz = 1024;
constexpr int Mz = Bz * Tz;           // 32768 rows
constexpr int Sz = 32, Lz = 128;      // scan: 32 chunks x 128 steps = T

using bf16x8  = __attribute__((ext_vector_type(8))) __bf16;
using floatx4 = __attribute__((ext_vector_type(4))) float;

DEV float bf2f(unsigned short u) { return __uint_as_float(((uint32_t)u) << 16); }
DEV unsigned short f2bf(float f) {            // round-to-nearest-even
    uint32_t u = __float_as_uint(f);
    u += 0x7fffu + ((u >> 16) & 1u);
    return (unsigned short)(u >> 16);
}
DEV unsigned short f2h(float f) {
    _Float16 h = (_Float16)f;
    unsigned short u;
    __builtin_memcpy(&u, &h, 2);
    return u;
}
DEV float h2f(unsigned short u) {
    _Float16 h;
    __builtin_memcpy(&h, &u, 2);
    return (float)h;
}

DEV void gl2lds16(const unsigned short* g, unsigned short* l) {
    __builtin_amdgcn_global_load_lds(
        (const __attribute__((address_space(1))) void*)g,
        (__attribute__((address_space(3))) void*)l, 16, 0, 0);
}

DEV void barmem() {
    asm volatile("" ::: "memory");
    __builtin_amdgcn_s_barrier();
    asm volatile("" ::: "memory");
}

// swizzled fragment read: LDS granule (row, cg) holds global granule cg^(row&7)
DEV bf16x8 ldfrag(const unsigned short* slot, int row, int kg) {
    return *(const bf16x8*)&slot[row * 64 + ((kg ^ (row & 7)) << 3)];
}

// ---------------- weight fp32 -> bf16 (all 4 weights, one dispatch) ----------------
__global__ __launch_bounds__(256) void f2b_k(const float* __restrict__ w0,
                                             const float* __restrict__ w1,
                                             const float* __restrict__ w2,
                                             const float* __restrict__ w3,
                                             unsigned short* __restrict__ dst) {
    int which = blockIdx.y;
    const float* src = which == 0 ? w0 : which == 1 ? w1 : which == 2 ? w2 : w3;
    int i = blockIdx.x * 256 + threadIdx.x;          // float4 idx within one weight
    float4 v = ((const float4*)src)[i];
    ushort4 o;
    o.x = f2bf(v.x); o.y = f2bf(v.y); o.z = f2bf(v.z); o.w = f2bf(v.w);
    ((ushort4*)(dst + (size_t)which * Cz * Cz))[i] = o;
}

// ---------------- time-mix: xk/xv/xr (bf16) ----------------
DEV ushort4 mix4(float4 m, float4 xc, float4 xp) {
    ushort4 o;
    o.x = f2bf(fmaf(m.x, xc.x - xp.x, xp.x));
    o.y = f2bf(fmaf(m.y, xc.y - xp.y, xp.y));
    o.z = f2bf(fmaf(m.z, xc.z - xp.z, xp.z));
    o.w = f2bf(fmaf(m.w, xc.w - xp.w, xp.w));
    return o;
}

__global__ __launch_bounds__(256) void mix_k(const float* __restrict__ x,
    const float* __restrict__ mk, const float* __restrict__ mv, const float* __restrict__ mr,
    unsigned short* __restrict__ xk, unsigned short* __restrict__ xv,
    unsigned short* __restrict__ xr) {
    int gid = blockIdx.x * 256 + threadIdx.x;       // float4 group; total Mz*Cz/4
    int m   = gid >> 8;                             // row = b*T + t   (Cz/4 = 256)
    int c4  = gid & 255;
    float4 xc = ((const float4*)x)[gid];
    float4 xp = make_float4(0.f, 0.f, 0.f, 0.f);
    if ((m & (Tz - 1)) != 0) xp = ((const float4*)x)[gid - 256];   // x[b, t-1]
    ((ushort4*)xk)[gid] = mix4(((const float4*)mk)[c4], xc, xp);
    ((ushort4*)xv)[gid] = mix4(((const float4*)mv)[c4], xc, xp);
    ((ushort4*)xr)[gid] = mix4(((const float4*)mr)[c4], xc, xp);
}

// ---------------- bf16 NT GEMM, 256x256 tile, BK=64 -------------------------------
// C[m,n] = sum_k A[m,k] * Bw[n,k];  M=32768, N=K=1024
// v2 schedule: ALL 24 fragment ds_reads issued at tile start (M0 operands first),
// MFMA quads run back-to-back with compiler-counted lgkmcnt waits -> LDS pipe
// overlaps matrix pipe within each wave. 2 barriers/tile (was 8).
// Stage ledger (8-slot ring, 16 KB half-tile slots):
//   early stages (tile t): h=4t+6,4t+7 = tile t+1 B halves -> opposite slot group
//   late  stages (tile t): h=4t+8,4t+9 = tile t+2 A halves -> THIS tile's drained
//     A slots (issued after lgkmcnt(0)+barrier)
//   boundary: vmcnt(4) leaves the 2 late stage-events in flight (vmcnt(0) at tail)
__global__ __launch_bounds__(512, 2) void gemm256(
        const unsigned short* __restrict__ A0, const unsigned short* __restrict__ A1,
        const unsigned short* __restrict__ A2,
        const unsigned short* __restrict__ Bw0, const unsigned short* __restrict__ Bw1,
        const unsigned short* __restrict__ Bw2,
        void* __restrict__ O0, void* __restrict__ O1, void* __restrict__ O2,
        int modes) {
    constexpr int Kd = 1024, Nd = 1024, NT = 16;       // NT = K / 64
    __shared__ __align__(16) unsigned short lds[8 * 8192];   // 128 KiB

    // bijective XCD swizzle (gridDim.x % 8 == 0)
    const int cpx = gridDim.x >> 3;
    const int L   = (blockIdx.x & 7) * cpx + (blockIdx.x >> 3);
    const int z   = L >> 9;                 // 512 wg per gemm
    const int rr  = L & 511;
    const int m0  = (rr >> 2) << 8;         // 128 m-blocks
    const int n0  = (rr & 3) << 8;          // 4 n-blocks

    const unsigned short* A  = z == 0 ? A0  : z == 1 ? A1  : A2;
    const unsigned short* Bw = z == 0 ? Bw0 : z == 1 ? Bw1 : Bw2;
    void* Cout = z == 0 ? O0 : z == 1 ? O1 : O2;
    const int mode = (modes >> (z * 4)) & 15;

    const int tid  = threadIdx.x;
    const int lane = tid & 63;
    const int wave = tid >> 6;              // 0..7
    const int wr   = wave >> 2;             // row half of the 256-tile
    const int wc   = wave & 3;              // col quarter (64 wide)
    const int l15  = lane & 15, kseg = lane >> 4;
    const int brow = (wc & 1) * 64;         // B row base within its half slot

    // staging constants: thread covers granules g0 and g0+64 of each half-tile
    const int g0   = wave * 128 + lane;
    const int row0 = g0 >> 3;
    const int scg0 = (g0 & 7) ^ (row0 & 7); // pre-swizzled global granule
    const size_t soff0 = (size_t)row0 * Kd + scg0 * 8;
    const int sd0  = g0 * 8;                // linear LDS dest (ushort)

    auto STAGE = [&](int hh) {
        if (hh >= 4 * NT) return;
        const int kind = hh & 3;
        const unsigned short* mat = (kind & 2) ? Bw : A;
        const int rbase = ((kind & 2) ? n0 : m0) + ((kind & 1) << 7);
        const unsigned short* sb = mat + (size_t)rbase * Kd + ((hh >> 2) << 6);
        unsigned short* db = &lds[(hh & 7) * 8192];
        gl2lds16(sb + soff0,            db + sd0);
        gl2lds16(sb + soff0 + 8 * Kd,   db + sd0 + 512);   // row+8, same swizzle
    };

    floatx4 acc[8][4];
#pragma unroll
    for (int mi = 0; mi < 8; mi++)
#pragma unroll
        for (int ni = 0; ni < 4; ni++) acc[mi][ni] = (floatx4){0.f, 0.f, 0.f, 0.f};

    auto QUAD = [&](const bf16x8 (&af)[4], const bf16x8 (&bfv)[4], int mo) {
#pragma unroll
        for (int i = 0; i < 4; i++)
#pragma unroll
            for (int n = 0; n < 4; n++)
                acc[mo + i][n] = __builtin_amdgcn_mfma_f32_16x16x32_bf16(
                    af[i], bfv[n], acc[mo + i][n], 0, 0, 0);
    };

    // prologue: tile0 (h0-3) + tile1 A halves (h4,5); need h0-3 done -> vmcnt(4)
#pragma unroll
    for (int hh = 0; hh < 6; hh++) STAGE(hh);
    asm volatile("s_waitcnt vmcnt(4)" ::: "memory");
    barmem();

#pragma unroll 2
    for (int t = 0; t < NT; t++) {
        const unsigned short* sA = &lds[(((t & 1) << 2) + wr) * 8192];
        const unsigned short* sB = &lds[(((t & 1) << 2) + 2 + (wc >> 1)) * 8192];
        const int bh = 4 * t + 6;
        bf16x8 a00[4], a01[4], a10[4], a11[4], b0[4], b1[4];

        // ---- all fragment reads, M0 operands first (compiler emits counted
        //      lgkmcnt before each QUAD; later reads retire under earlier MFMAs)
#pragma unroll
        for (int i = 0; i < 4; i++) {
            a00[i] = ldfrag(sA, i * 16 + l15, kseg);
            b0[i]  = ldfrag(sB, brow + i * 16 + l15, kseg);
        }
#pragma unroll
        for (int i = 0; i < 4; i++)
            a10[i] = ldfrag(sA, 64 + i * 16 + l15, kseg);
#pragma unroll
        for (int i = 0; i < 4; i++) {
            a01[i] = ldfrag(sA, i * 16 + l15, 4 + kseg);
            a11[i] = ldfrag(sA, 64 + i * 16 + l15, 4 + kseg);
            b1[i]  = ldfrag(sB, brow + i * 16 + l15, 4 + kseg);
        }

        STAGE(bh + 0);     // tile t+1 B half 0 -> opposite slot group (safe)
        STAGE(bh + 1);     // tile t+1 B half 1 -> opposite slot group (safe)

        __builtin_amdgcn_s_setprio(1);
        QUAD(a00, b0, 0);
        QUAD(a10, b0, 4);
        QUAD(a01, b1, 0);
        QUAD(a11, b1, 4);
        __builtin_amdgcn_s_setprio(0);

        // all this tile's ds_reads retired (in-order DS) before A slots reused
        asm volatile("s_waitcnt lgkmcnt(0)" ::: "memory");
        barmem();

        STAGE(bh + 2);     // tile t+2 A half 0 -> this tile's A slot 0 (drained)
        STAGE(bh + 3);     // tile t+2 A half 1 -> this tile's A slot 1 (drained)

        if (t < NT - 2) asm volatile("s_waitcnt vmcnt(4)" ::: "memory");
        else            asm volatile("s_waitcnt vmcnt(0)" ::: "memory");
        barmem();
    }

    // epilogue: D col = lane&15, row = (lane>>4)*4 + reg   [m89 verified]
    const int cr = kseg * 4;
#pragma unroll
    for (int mi = 0; mi < 8; mi++) {
#pragma unroll
        for (int ni = 0; ni < 4; ni++) {
            size_t row = (size_t)(m0 + wr * 128 + mi * 16 + cr);
            size_t col = (size_t)(n0 + wc * 64 + ni * 16 + l15);
#pragma unroll
            for (int rg = 0; rg < 4; rg++) {
                float v = acc[mi][ni][rg];
                size_t idx = (row + rg) * Nd + col;
                if (mode == 0) {
                    ((float*)Cout)[idx] = v;
                } else if (mode == 1) {
                    ((unsigned short*)Cout)[idx] = f2bf(v);
                } else if (mode == 2) {
                    float sg = 1.0f / (1.0f + __expf(-v));
                    ((unsigned short*)Cout)[idx] = f2bf(sg);
                } else {
                    ((unsigned short*)Cout)[idx] = f2h(v);
                }
            }
        }
    }
}

// ---------------- WKV scan, 3-pass chunked linear recurrence ----------------
__global__ __launch_bounds__(256) void wkv_pass1(const unsigned short* __restrict__ kh,
    const unsigned short* __restrict__ vb, const float* __restrict__ td,
    float2* __restrict__ SA, float2* __restrict__ SB) {
    int tid = blockIdx.x * 256 + threadIdx.x;   // B*S*C/2 threads
    int c2  = tid & 511;
    int bs  = tid >> 9;                         // b*S + s
    int b   = bs >> 5, s = bs & (Sz - 1);
    int c   = c2 * 2;
    float lam0 = __expf(-__expf(td[c]));
    float lam1 = __expf(-__expf(td[c + 1]));
    size_t base = (((size_t)(b * Tz + s * Lz)) * Cz + c) >> 1;   // ushort2 index
    float pa0 = 0.f, pb0 = 0.f, pa1 = 0.f, pb1 = 0.f;
#pragma unroll 4
    for (int i = 0; i < Lz; i++) {
        size_t idx = base + (size_t)i * (Cz / 2);
        ushort2 kk = ((const ushort2*)kh)[idx];
        ushort2 vv = ((const ushort2*)vb)[idx];
        float e0 = __expf(h2f(kk.x)), e1 = __expf(h2f(kk.y));
        pa0 = fmaf(pa0, lam0, e0 * bf2f(vv.x));
        pb0 = fmaf(pb0, lam0, e0);
        pa1 = fmaf(pa1, lam1, e1 * bf2f(vv.y));
        pb1 = fmaf(pb1, lam1, e1);
    }
    SA[tid] = make_float2(pa0, pa1);   // layout (b*S+s)*512 + c2
    SB[tid] = make_float2(pb0, pb1);
}

__global__ __launch_bounds__(256) void wkv_pass2(const float* __restrict__ td,
                                                 float2* __restrict__ SA,
                                                 float2* __restrict__ SB) {
    int tid = blockIdx.x * 256 + threadIdx.x;   // B*C/2 threads
    int c2  = tid & 511;
    int b   = tid >> 9;
    int c   = c2 * 2;
    float lamL0 = __expf(-__expf(td[c]) * (float)Lz);
    float lamL1 = __expf(-__expf(td[c + 1]) * (float)Lz);
    float A0 = 0.f, B0 = 0.f, A1 = 0.f, B1 = 0.f;
    for (int s = 0; s < Sz; s++) {
        size_t idx = ((size_t)(b * Sz + s)) * 512 + c2;
        float2 ta = SA[idx], tb = SB[idx];
        SA[idx] = make_float2(A0, A1);          // exclusive prefix = chunk-start state
        SB[idx] = make_float2(B0, B1);
        A0 = fmaf(A0, lamL0, ta.x);  B0 = fmaf(B0, lamL0, tb.x);
        A1 = fmaf(A1, lamL1, ta.y);  B1 = fmaf(B1, lamL1, tb.y);
    }
}

__global__ __launch_bounds__(256) void wkv_pass3(const unsigned short* __restrict__ kh,
    const unsigned short* __restrict__ vb, const unsigned short* __restrict__ rb,
    const float* __restrict__ td, const float* __restrict__ tf,
    const float2* __restrict__ SA, const float2* __restrict__ SB,
    unsigned short* __restrict__ ry) {
    int tid = blockIdx.x * 256 + threadIdx.x;
    int c2  = tid & 511;
    int bs  = tid >> 9;
    int b   = bs >> 5, s = bs & (Sz - 1);
    int c   = c2 * 2;
    float lam0 = __expf(-__expf(td[c]));
    float lam1 = __expf(-__expf(td[c + 1]));
    float eu0  = __expf(tf[c]);
    float eu1  = __expf(tf[c + 1]);
    float2 fa = SA[tid], fb = SB[tid];
    float A0 = fa.x, A1 = fa.y, B0 = fb.x, B1 = fb.y;
    size_t base = (((size_t)(b * Tz + s * Lz)) * Cz + c) >> 1;
#pragma unroll 2
    for (int i = 0; i < Lz; i++) {
        size_t idx = base + (size_t)i * (Cz / 2);
        ushort2 kk = ((const ushort2*)kh)[idx];
        ushort2 vv = ((const ushort2*)vb)[idx];
        ushort2 rr = ((const ushort2*)rb)[idx];
        float e0 = __expf(h2f(kk.x)), e1 = __expf(h2f(kk.y));
        float ev0 = e0 * bf2f(vv.x), ev1 = e1 * bf2f(vv.y);
        float y0 = fmaf(A0, eu0, ev0) * __builtin_amdgcn_rcpf(fmaf(B0, eu0, e0));
        float y1 = fmaf(A1, eu1, ev1) * __builtin_amdgcn_rcpf(fmaf(B1, eu1, e1));
        ushort2 o;
        o.x = f2bf(bf2f(rr.x) * y0);
        o.y = f2bf(bf2f(rr.y) * y1);
        ((ushort2*)ry)[idx] = o;
        A0 = fmaf(A0, lam0, ev0);  B0 = fmaf(B0, lam0, e0);
        A1 = fmaf(A1, lam1, ev1);  B1 = fmaf(B1, lam1, e1);
    }
}

// ---------------- launcher ----------------
extern "C" void kernel_launch(void* const* d_in, const int* in_sizes, int n_in,
                              void* d_out, int out_size, void* d_ws, size_t ws_size,
                              hipStream_t stream) {
    const float* x  = (const float*)d_in[0];
    const float* td = (const float*)d_in[1];
    const float* tf = (const float*)d_in[2];
    const float* mk = (const float*)d_in[3];
    const float* mv = (const float*)d_in[4];
    const float* mr = (const float*)d_in[5];
    const float* Wk = (const float*)d_in[6];
    const float* Wv = (const float*)d_in[7];
    const float* Wr = (const float*)d_in[8];
    const float* Wo = (const float*)d_in[9];

    constexpr size_t SZ_BF = (size_t)Mz * Cz * 2;       // 64 MB
    constexpr size_t SZ_W  = (size_t)Cz * Cz * 2;       // 2 MB
    constexpr size_t SZ_S  = (size_t)Bz * Sz * Cz * 4;  // 1 MB

    char* ws = (char*)d_ws;
    unsigned short* xk  = (unsigned short*)(ws);
    unsigned short* xv  = (unsigned short*)(ws + SZ_BF);
    unsigned short* xr  = (unsigned short*)(ws + 2 * SZ_BF);
    unsigned short* kf  = (unsigned short*)(ws + 3 * SZ_BF);   // f16
    unsigned short* vb  = (unsigned short*)(ws + 4 * SZ_BF);   // bf16
    unsigned short* rb  = (unsigned short*)(ws + 5 * SZ_BF);   // bf16
    unsigned short* wts = (unsigned short*)(ws + 6 * SZ_BF);   // wk|wv|wr|wo
    float2*         SA  = (float2*)        (ws + 6 * SZ_BF + 4 * SZ_W);
    float2*         SB  = (float2*)        (ws + 6 * SZ_BF + 4 * SZ_W + SZ_S);
    unsigned short* wkb = wts;
    unsigned short* wvb = wts + (size_t)Cz * Cz;
    unsigned short* wrb = wts + (size_t)2 * Cz * Cz;
    unsigned short* wob = wts + (size_t)3 * Cz * Cz;
    unsigned short* ry  = xk;   // xk dead after k-GEMM; reuse for r*y

    f2b_k<<<dim3(Cz * Cz / 4 / 256, 4), dim3(256), 0, stream>>>(Wk, Wv, Wr, Wo, wts);

    mix_k<<<dim3(Mz * Cz / 4 / 256), dim3(256), 0, stream>>>(x, mk, mv, mr, xk, xv, xr);

    // fused k/v/r GEMMs: z=0 k->f16, z=1 v->bf16, z=2 r->sigmoid bf16
    gemm256<<<dim3(512 * 3), dim3(512), 0, stream>>>(
        xk, xv, xr, wkb, wvb, wrb, (void*)kf, (void*)vb, (void*)rb,
        (3) | (1 << 4) | (2 << 8));

    wkv_pass1<<<dim3(Bz * Sz * Cz / 2 / 256), dim3(256), 0, stream>>>(kf, vb, td, SA, SB);
    wkv_pass2<<<dim3(Bz * Cz / 2 / 256), dim3(256), 0, stream>>>(td, SA, SB);
    wkv_pass3<<<dim3(Bz * Sz * Cz / 2 / 256), dim3(256), 0, stream>>>(kf, vb, rb, td, tf,
                                                                      SA, SB, ry);

    // out = (r*y) @ Wo^T, fp32
    gemm256<<<dim3(512), dim3(512), 0, stream>>>(
        ry, ry, ry, wob, wob, wob, d_out, d_out, d_out, 0);
}

// Round 4
// 703.207 us; speedup vs baseline: 1.0630x; 1.0630x over previous
//
#include <hip/hip_runtime.h>
#include <cstdint>

#define DEV __device__ __forceinline__

constexpr int Bz = 8, Tz = 4096, Cz = 1024;
constexpr int Mz = Bz * Tz;           // 32768 rows
constexpr int Sz = 32, Lz = 128;      // scan: 32 chunks x 128 steps = T

using bf16x8  = __attribute__((ext_vector_type(8))) __bf16;
using floatx4 = __attribute__((ext_vector_type(4))) float;

DEV float bf2f(unsigned short u) { return __uint_as_float(((uint32_t)u) << 16); }
DEV unsigned short f2bf(float f) {            // round-to-nearest-even
    uint32_t u = __float_as_uint(f);
    u += 0x7fffu + ((u >> 16) & 1u);
    return (unsigned short)(u >> 16);
}
DEV unsigned short f2h(float f) {
    _Float16 h = (_Float16)f;
    unsigned short u;
    __builtin_memcpy(&u, &h, 2);
    return u;
}
DEV float h2f(unsigned short u) {
    _Float16 h;
    __builtin_memcpy(&h, &u, 2);
    return (float)h;
}

DEV void gl2lds16(const unsigned short* g, unsigned short* l) {
    __builtin_amdgcn_global_load_lds(
        (const __attribute__((address_space(1))) void*)g,
        (__attribute__((address_space(3))) void*)l, 16, 0, 0);
}

DEV void barmem() {
    asm volatile("" ::: "memory");
    __builtin_amdgcn_s_barrier();
    asm volatile("" ::: "memory");
}

// ---------------- weight fp32 -> bf16 (all 4 weights, one dispatch) ----------------
__global__ __launch_bounds__(256) void f2b_k(const float* __restrict__ w0,
                                             const float* __restrict__ w1,
                                             const float* __restrict__ w2,
                                             const float* __restrict__ w3,
                                             unsigned short* __restrict__ dst) {
    int which = blockIdx.y;
    const float* src = which == 0 ? w0 : which == 1 ? w1 : which == 2 ? w2 : w3;
    int i = blockIdx.x * 256 + threadIdx.x;          // float4 idx within one weight
    float4 v = ((const float4*)src)[i];
    ushort4 o;
    o.x = f2bf(v.x); o.y = f2bf(v.y); o.z = f2bf(v.z); o.w = f2bf(v.w);
    ((ushort4*)(dst + (size_t)which * Cz * Cz))[i] = o;
}

// ---------------- time-mix: xk/xv/xr (bf16) ----------------
DEV ushort4 mix4(float4 m, float4 xc, float4 xp) {
    ushort4 o;
    o.x = f2bf(fmaf(m.x, xc.x - xp.x, xp.x));
    o.y = f2bf(fmaf(m.y, xc.y - xp.y, xp.y));
    o.z = f2bf(fmaf(m.z, xc.z - xp.z, xp.z));
    o.w = f2bf(fmaf(m.w, xc.w - xp.w, xp.w));
    return o;
}

__global__ __launch_bounds__(256) void mix_k(const float* __restrict__ x,
    const float* __restrict__ mk, const float* __restrict__ mv, const float* __restrict__ mr,
    unsigned short* __restrict__ xk, unsigned short* __restrict__ xv,
    unsigned short* __restrict__ xr) {
    int gid = blockIdx.x * 256 + threadIdx.x;       // float4 group; total Mz*Cz/4
    int m   = gid >> 8;                             // row = b*T + t   (Cz/4 = 256)
    int c4  = gid & 255;
    float4 xc = ((const float4*)x)[gid];
    float4 xp = make_float4(0.f, 0.f, 0.f, 0.f);
    if ((m & (Tz - 1)) != 0) xp = ((const float4*)x)[gid - 256];   // x[b, t-1]
    ((ushort4*)xk)[gid] = mix4(((const float4*)mk)[c4], xc, xp);
    ((ushort4*)xv)[gid] = mix4(((const float4*)mv)[c4], xc, xp);
    ((ushort4*)xr)[gid] = mix4(((const float4*)mr)[c4], xc, xp);
}

// ---------------- bf16 NT GEMM, 256x256 tile, BK=64, 4-phase, vmcnt-BEFORE-barrier --
// C[m,n] = sum_k A[m,k] * Bw[n,k];  M=32768, N=K=1024
// Slots: 8 x 16KB, 2-tile ring; group (t&1): {Ak0,Ak1,Bk0,Bk1}, each [256 rows][32 k]
// bf16, granule XOR-swizzle g^((r>>1)&3) (involution on stage source and ds_read).
// Phase: reads -> stage -> barrier -> lgkmcnt(0)+schedbar -> setprio+16 MFMA -> barrier.
// Stage schedule: q0:Ak1(t+1) q1:Bk1(t+1) q2:Ak0(t+2) q3:Bk0(t+2).
// Counted waits placed BEFORE the barrier (vmcnt is per-wave; barrier publishes):
//   W1 = vmcnt(8) end of P1 (drains Ak1(t),Bk1(t) for P2 reads)
//   W2 = vmcnt(8) end of P3 (drains Ak0(t+1),Bk0(t+1) for next P0 reads)
// Tail: t=14 W2=4; t=15 W1=0, W2 skipped.  Never vmcnt(0) mid-loop.
__global__ __launch_bounds__(512, 2) void gemm256(
        const unsigned short* __restrict__ A0, const unsigned short* __restrict__ A1,
        const unsigned short* __restrict__ A2,
        const unsigned short* __restrict__ Bw0, const unsigned short* __restrict__ Bw1,
        const unsigned short* __restrict__ Bw2,
        void* __restrict__ O0, void* __restrict__ O1, void* __restrict__ O2,
        int modes) {
    constexpr int Kd = 1024, Nd = 1024, NT = 16;       // NT = K / 64
    __shared__ __align__(16) unsigned short lds[8 * 8192];   // 128 KiB

    // bijective XCD swizzle (gridDim.x % 8 == 0)
    const int cpx = gridDim.x >> 3;
    const int L   = (blockIdx.x & 7) * cpx + (blockIdx.x >> 3);
    const int z   = L >> 9;                 // 512 wg per gemm
    const int rr  = L & 511;
    const int m0  = (rr >> 2) << 8;         // 128 m-blocks
    const int n0  = (rr & 3) << 8;          // 4 n-blocks

    const unsigned short* A  = z == 0 ? A0  : z == 1 ? A1  : A2;
    const unsigned short* Bw = z == 0 ? Bw0 : z == 1 ? Bw1 : Bw2;
    void* Cout = z == 0 ? O0 : z == 1 ? O1 : O2;
    const int mode = (modes >> (z * 4)) & 15;

    const int tid  = threadIdx.x;
    const int lane = tid & 63;
    const int wave = tid >> 6;              // 0..7
    const int wr   = wave >> 2;             // A row half (128 rows)
    const int wc   = wave & 3;              // B col quarter (64 cols)
    const int l15  = lane & 15, kseg = lane >> 4;
    const int wr128 = wr * 128, wc64 = wc * 64;

    // staging: thread covers granules gi and gi+512 of each 16KB slot
    const int gi   = wave * 64 + lane;      // 0..511
    const int srow = gi >> 2;               // 0..127 (and +128 for 2nd call)
    const int sg   = (gi & 3) ^ ((srow >> 1) & 3);   // pre-swizzled global granule
    const size_t sofs = (size_t)srow * Kd + sg * 8;
    const int gi8  = gi * 8;

    auto STAGE = [&](int kind, int tt) {    // kind 0=Ak0 1=Ak1 2=Bk0 3=Bk1
        const unsigned short* mat = (kind >= 2) ? Bw : A;
        const int rb = (kind >= 2) ? n0 : m0;
        const unsigned short* sb = mat + (size_t)rb * Kd + tt * 64 + (kind & 1) * 32;
        unsigned short* db = &lds[(((tt & 1) << 2) + kind) * 8192];
        gl2lds16(sb + sofs,                    db + gi8);
        gl2lds16(sb + sofs + (size_t)128 * Kd, db + gi8 + 4096);
    };

    // swizzled fragment read from a [256][32] slot
    auto LDF = [&](const unsigned short* slot, int row) -> bf16x8 {
        return *(const bf16x8*)&slot[row * 32 + ((kseg ^ ((row >> 1) & 3)) << 3)];
    };

    floatx4 acc[8][4];
#pragma unroll
    for (int mi = 0; mi < 8; mi++)
#pragma unroll
        for (int ni = 0; ni < 4; ni++) acc[mi][ni] = (floatx4){0.f, 0.f, 0.f, 0.f};

    auto QUAD = [&](const bf16x8 (&af)[4], const bf16x8 (&bfv)[4], int mo) {
#pragma unroll
        for (int i = 0; i < 4; i++)
#pragma unroll
            for (int n = 0; n < 4; n++)
                acc[mo + i][n] = __builtin_amdgcn_mfma_f32_16x16x32_bf16(
                    af[i], bfv[n], acc[mo + i][n], 0, 0, 0);
    };

    auto VMW = [&](int n) {                 // counted vmcnt + sched pin (rule 18)
        if (n == 8)      { asm volatile("s_waitcnt vmcnt(8)" ::: "memory"); }
        else if (n == 4) { asm volatile("s_waitcnt vmcnt(4)" ::: "memory"); }
        else             { asm volatile("s_waitcnt vmcnt(0)" ::: "memory"); }
        __builtin_amdgcn_sched_barrier(0);
    };
    auto LKW = [&]() {
        asm volatile("s_waitcnt lgkmcnt(0)" ::: "memory");
        __builtin_amdgcn_sched_barrier(0);
    };

    auto TILE = [&](int t, bool s01, bool s23, int w1, int w2) {
        const unsigned short* Ak0 = &lds[((t & 1) << 2) * 8192];
        const unsigned short* Ak1 = Ak0 + 8192;
        const unsigned short* Bk0 = Ak0 + 2 * 8192;
        const unsigned short* Bk1 = Ak0 + 3 * 8192;
        bf16x8 fa[4], fb[4];

        // ---- P0: reads Ak0(lo)+Bk0 (8); MFMA Q0
#pragma unroll
        for (int i = 0; i < 4; i++) {
            fa[i] = LDF(Ak0, wr128 + i * 16 + l15);
            fb[i] = LDF(Bk0, wc64 + i * 16 + l15);
        }
        if (s01) STAGE(1, t + 1);            // Ak1(t+1), opposite group
        barmem();
        LKW();
        __builtin_amdgcn_s_setprio(1);
        QUAD(fa, fb, 0);
        __builtin_amdgcn_s_setprio(0);
        barmem();

        // ---- P1: reads Ak0(hi) (4); MFMA Q1 (fb reused)
#pragma unroll
        for (int i = 0; i < 4; i++)
            fa[i] = LDF(Ak0, wr128 + 64 + i * 16 + l15);
        if (s01) STAGE(3, t + 1);            // Bk1(t+1), opposite group
        barmem();
        LKW();
        __builtin_amdgcn_s_setprio(1);
        QUAD(fa, fb, 4);
        __builtin_amdgcn_s_setprio(0);
        VMW(w1);                             // drain Ak1(t),Bk1(t) BEFORE barrier
        barmem();

        // ---- P2: reads Ak1(lo)+Bk1 (8); MFMA Q2
#pragma unroll
        for (int i = 0; i < 4; i++) {
            fa[i] = LDF(Ak1, wr128 + i * 16 + l15);
            fb[i] = LDF(Bk1, wc64 + i * 16 + l15);
        }
        if (s23) STAGE(0, t + 2);            // Ak0(t+2) = this group's Ak0 (drained)
        barmem();
        LKW();
        __builtin_amdgcn_s_setprio(1);
        QUAD(fa, fb, 0);
        __builtin_amdgcn_s_setprio(0);
        barmem();

        // ---- P3: reads Ak1(hi) (4); MFMA Q3
#pragma unroll
        for (int i = 0; i < 4; i++)
            fa[i] = LDF(Ak1, wr128 + 64 + i * 16 + l15);
        if (s23) STAGE(2, t + 2);            // Bk0(t+2) = this group's Bk0 (drained)
        barmem();
        LKW();
        __builtin_amdgcn_s_setprio(1);
        QUAD(fa, fb, 4);
        __builtin_amdgcn_s_setprio(0);
        if (w2 >= 0) VMW(w2);                // drain Ak0(t+1),Bk0(t+1) BEFORE barrier
        barmem();
    };

    // prologue stages, event order e1..e12:
    STAGE(0, 0); STAGE(2, 0);               // Ak0(0) e1-2, Bk0(0) e3-4
    STAGE(1, 0); STAGE(3, 0);               // Ak1(0) e5-6, Bk1(0) e7-8
    STAGE(0, 1); STAGE(2, 1);               // Ak0(1) e9-10, Bk0(1) e11-12
    VMW(8);                                  // drain e1-e4 (tile-0 P0 operands)
    barmem();

#pragma unroll 2
    for (int t = 0; t < NT - 2; t++)        // t = 0..13: all stages live
        TILE(t, true, true, 8, 8);
    TILE(NT - 2, true, false, 8, 4);        // t=14: no t+2 stages
    TILE(NT - 1, false, false, 0, -1);      // t=15: drain

    // epilogue: D col = lane&15, row = (lane>>4)*4 + reg   [m89 verified]
    const int cr = kseg * 4;
#pragma unroll
    for (int mi = 0; mi < 8; mi++) {
#pragma unroll
        for (int ni = 0; ni < 4; ni++) {
            size_t row = (size_t)(m0 + wr128 + mi * 16 + cr);
            size_t col = (size_t)(n0 + wc64 + ni * 16 + l15);
#pragma unroll
            for (int rg = 0; rg < 4; rg++) {
                float v = acc[mi][ni][rg];
                size_t idx = (row + rg) * Nd + col;
                if (mode == 0) {
                    ((float*)Cout)[idx] = v;
                } else if (mode == 1) {
                    ((unsigned short*)Cout)[idx] = f2bf(v);
                } else if (mode == 2) {
                    float sg2 = 1.0f / (1.0f + __expf(-v));
                    ((unsigned short*)Cout)[idx] = f2bf(sg2);
                } else {
                    ((unsigned short*)Cout)[idx] = f2h(v);
                }
            }
        }
    }
}

// ---------------- WKV scan, 3-pass chunked linear recurrence ----------------
__global__ __launch_bounds__(256) void wkv_pass1(const unsigned short* __restrict__ kh,
    const unsigned short* __restrict__ vb, const float* __restrict__ td,
    float2* __restrict__ SA, float2* __restrict__ SB) {
    int tid = blockIdx.x * 256 + threadIdx.x;   // B*S*C/2 threads
    int c2  = tid & 511;
    int bs  = tid >> 9;                         // b*S + s
    int b   = bs >> 5, s = bs & (Sz - 1);
    int c   = c2 * 2;
    float lam0 = __expf(-__expf(td[c]));
    float lam1 = __expf(-__expf(td[c + 1]));
    size_t base = (((size_t)(b * Tz + s * Lz)) * Cz + c) >> 1;   // ushort2 index
    float pa0 = 0.f, pb0 = 0.f, pa1 = 0.f, pb1 = 0.f;
#pragma unroll 4
    for (int i = 0; i < Lz; i++) {
        size_t idx = base + (size_t)i * (Cz / 2);
        ushort2 kk = ((const ushort2*)kh)[idx];
        ushort2 vv = ((const ushort2*)vb)[idx];
        float e0 = __expf(h2f(kk.x)), e1 = __expf(h2f(kk.y));
        pa0 = fmaf(pa0, lam0, e0 * bf2f(vv.x));
        pb0 = fmaf(pb0, lam0, e0);
        pa1 = fmaf(pa1, lam1, e1 * bf2f(vv.y));
        pb1 = fmaf(pb1, lam1, e1);
    }
    SA[tid] = make_float2(pa0, pa1);   // layout (b*S+s)*512 + c2
    SB[tid] = make_float2(pb0, pb1);
}

__global__ __launch_bounds__(256) void wkv_pass2(const float* __restrict__ td,
                                                 float2* __restrict__ SA,
                                                 float2* __restrict__ SB) {
    int tid = blockIdx.x * 256 + threadIdx.x;   // B*C/2 threads
    int c2  = tid & 511;
    int b   = tid >> 9;
    int c   = c2 * 2;
    float lamL0 = __expf(-__expf(td[c]) * (float)Lz);
    float lamL1 = __expf(-__expf(td[c + 1]) * (float)Lz);
    float A0 = 0.f, B0 = 0.f, A1 = 0.f, B1 = 0.f;
    for (int s = 0; s < Sz; s++) {
        size_t idx = ((size_t)(b * Sz + s)) * 512 + c2;
        float2 ta = SA[idx], tb = SB[idx];
        SA[idx] = make_float2(A0, A1);          // exclusive prefix = chunk-start state
        SB[idx] = make_float2(B0, B1);
        A0 = fmaf(A0, lamL0, ta.x);  B0 = fmaf(B0, lamL0, tb.x);
        A1 = fmaf(A1, lamL1, ta.y);  B1 = fmaf(B1, lamL1, tb.y);
    }
}

__global__ __launch_bounds__(256) void wkv_pass3(const unsigned short* __restrict__ kh,
    const unsigned short* __restrict__ vb, const unsigned short* __restrict__ rb,
    const float* __restrict__ td, const float* __restrict__ tf,
    const float2* __restrict__ SA, const float2* __restrict__ SB,
    unsigned short* __restrict__ ry) {
    int tid = blockIdx.x * 256 + threadIdx.x;
    int c2  = tid & 511;
    int bs  = tid >> 9;
    int b   = bs >> 5, s = bs & (Sz - 1);
    int c   = c2 * 2;
    float lam0 = __expf(-__expf(td[c]));
    float lam1 = __expf(-__expf(td[c + 1]));
    float eu0  = __expf(tf[c]);
    float eu1  = __expf(tf[c + 1]);
    float2 fa = SA[tid], fb = SB[tid];
    float A0 = fa.x, A1 = fa.y, B0 = fb.x, B1 = fb.y;
    size_t base = (((size_t)(b * Tz + s * Lz)) * Cz + c) >> 1;
#pragma unroll 2
    for (int i = 0; i < Lz; i++) {
        size_t idx = base + (size_t)i * (Cz / 2);
        ushort2 kk = ((const ushort2*)kh)[idx];
        ushort2 vv = ((const ushort2*)vb)[idx];
        ushort2 rr = ((const ushort2*)rb)[idx];
        float e0 = __expf(h2f(kk.x)), e1 = __expf(h2f(kk.y));
        float ev0 = e0 * bf2f(vv.x), ev1 = e1 * bf2f(vv.y);
        float y0 = fmaf(A0, eu0, ev0) * __builtin_amdgcn_rcpf(fmaf(B0, eu0, e0));
        float y1 = fmaf(A1, eu1, ev1) * __builtin_amdgcn_rcpf(fmaf(B1, eu1, e1));
        ushort2 o;
        o.x = f2bf(bf2f(rr.x) * y0);
        o.y = f2bf(bf2f(rr.y) * y1);
        ((ushort2*)ry)[idx] = o;
        A0 = fmaf(A0, lam0, ev0);  B0 = fmaf(B0, lam0, e0);
        A1 = fmaf(A1, lam1, ev1);  B1 = fmaf(B1, lam1, e1);
    }
}

// ---------------- launcher ----------------
extern "C" void kernel_launch(void* const* d_in, const int* in_sizes, int n_in,
                              void* d_out, int out_size, void* d_ws, size_t ws_size,
                              hipStream_t stream) {
    const float* x  = (const float*)d_in[0];
    const float* td = (const float*)d_in[1];
    const float* tf = (const float*)d_in[2];
    const float* mk = (const float*)d_in[3];
    const float* mv = (const float*)d_in[4];
    const float* mr = (const float*)d_in[5];
    const float* Wk = (const float*)d_in[6];
    const float* Wv = (const float*)d_in[7];
    const float* Wr = (const float*)d_in[8];
    const float* Wo = (const float*)d_in[9];

    constexpr size_t SZ_BF = (size_t)Mz * Cz * 2;       // 64 MB
    constexpr size_t SZ_W  = (size_t)Cz * Cz * 2;       // 2 MB
    constexpr size_t SZ_S  = (size_t)Bz * Sz * Cz * 4;  // 1 MB

    char* ws = (char*)d_ws;
    unsigned short* xk  = (unsigned short*)(ws);
    unsigned short* xv  = (unsigned short*)(ws + SZ_BF);
    unsigned short* xr  = (unsigned short*)(ws + 2 * SZ_BF);
    unsigned short* kf  = (unsigned short*)(ws + 3 * SZ_BF);   // f16
    unsigned short* vb  = (unsigned short*)(ws + 4 * SZ_BF);   // bf16
    unsigned short* rb  = (unsigned short*)(ws + 5 * SZ_BF);   // bf16
    unsigned short* wts = (unsigned short*)(ws + 6 * SZ_BF);   // wk|wv|wr|wo
    float2*         SA  = (float2*)        (ws + 6 * SZ_BF + 4 * SZ_W);
    float2*         SB  = (float2*)        (ws + 6 * SZ_BF + 4 * SZ_W + SZ_S);
    unsigned short* wkb = wts;
    unsigned short* wvb = wts + (size_t)Cz * Cz;
    unsigned short* wrb = wts + (size_t)2 * Cz * Cz;
    unsigned short* wob = wts + (size_t)3 * Cz * Cz;
    unsigned short* ry  = xk;   // xk dead after k-GEMM; reuse for r*y

    f2b_k<<<dim3(Cz * Cz / 4 / 256, 4), dim3(256), 0, stream>>>(Wk, Wv, Wr, Wo, wts);

    mix_k<<<dim3(Mz * Cz / 4 / 256), dim3(256), 0, stream>>>(x, mk, mv, mr, xk, xv, xr);

    // fused k/v/r GEMMs: z=0 k->f16, z=1 v->bf16, z=2 r->sigmoid bf16
    gemm256<<<dim3(512 * 3), dim3(512), 0, stream>>>(
        xk, xv, xr, wkb, wvb, wrb, (void*)kf, (void*)vb, (void*)rb,
        (3) | (1 << 4) | (2 << 8));

    wkv_pass1<<<dim3(Bz * Sz * Cz / 2 / 256), dim3(256), 0, stream>>>(kf, vb, td, SA, SB);
    wkv_pass2<<<dim3(Bz * Cz / 2 / 256), dim3(256), 0, stream>>>(td, SA, SB);
    wkv_pass3<<<dim3(Bz * Sz * Cz / 2 / 256), dim3(256), 0, stream>>>(kf, vb, rb, td, tf,
                                                                      SA, SB, ry);

    // out = (r*y) @ Wo^T, fp32
    gemm256<<<dim3(512), dim3(512), 0, stream>>>(
        ry, ry, ry, wob, wob, wob, d_out, d_out, d_out, 0);
}